// Round 4
// baseline (252.335 us; speedup 1.0000x reference)
//
#include <hip/hip_runtime.h>
#include <hip/hip_bf16.h>

// tanh(X @ W^T + b): M=131072, N=K=256, fp32 in/out.
// R7: R6 + distance-2 prefetch (triple-buffer LDS, 48 KB) + uniform
// vmcnt(12) so the awaited gload has a FULL iteration of slack and NT-store
// acks from iter j-1 get a full iteration to retire (R6's vmcnt(8) gated
// every iter on fresh loads + old store acks, in-order counter). Col-half
// siblings XCD-paired (bids 16p+x / 16p+x+8 share an XCD L2 rc-stream).
// Block = 16-row chunk x 128 cols, 4 waves x 32 cols (bW[8][2]=64 regs),
// fp32 X via global_load_lds with pre-swizzled source (0 bank conflicts),
// direct scalar NT stores. 768 blocks, 3 blocks/CU.

#define HIDDEN 256
#define M_TOTAL (16 * 8192)
#define NBLK 768
#define NSTREAM 384          // NBLK/2 rc-streams, 2 col-half blocks each

using bf16x8 = __attribute__((ext_vector_type(8))) __bf16;
using f32x4  = __attribute__((ext_vector_type(4))) float;

__device__ __forceinline__ void gload16(const void* g, void* l) {
    __builtin_amdgcn_global_load_lds(
        (const __attribute__((address_space(1))) void*)g,
        (__attribute__((address_space(3))) void*)l, 16, 0, 0);
}

// WF[((nb*8 + c)*4 + t)*512 + lane*8 + j] =
//   bf16( W[(nb*64 + t*16 + (lane&15))*256 + c*32 + (lane>>4)*8 + j] )
__global__ __launch_bounds__(256) void wfrag_kernel(const float* __restrict__ W,
                                                    __bf16* __restrict__ WF) {
    const int gid  = blockIdx.x * 256 + threadIdx.x;   // 0..8191
    const int lane = gid & 63;
    const int t    = (gid >> 6) & 3;
    const int c    = (gid >> 8) & 7;
    const int nb   = gid >> 11;
    const int lr = lane & 15, q = lane >> 4;
    const float* src = W + (size_t)(nb * 64 + t * 16 + lr) * HIDDEN + c * 32 + q * 8;
    float4 lo = *(const float4*)src;
    float4 hi = *(const float4*)(src + 4);
    bf16x8 v;
    v[0] = (__bf16)lo.x; v[1] = (__bf16)lo.y; v[2] = (__bf16)lo.z; v[3] = (__bf16)lo.w;
    v[4] = (__bf16)hi.x; v[5] = (__bf16)hi.y; v[6] = (__bf16)hi.z; v[7] = (__bf16)hi.w;
    *(bf16x8*)(WF + (size_t)gid * 8) = v;
}

__global__ __launch_bounds__(256, 3) void rotor_kernel(const float* __restrict__ X,
                                                       const __bf16* __restrict__ WF,
                                                       const float* __restrict__ bias,
                                                       float* __restrict__ Y) {
    // X triple-buffer: 3 x 16 rows x 256 fp32 = 48 KB.
    __shared__ __align__(16) float sX[3][16 * 256];

    const int tid  = threadIdx.x;
    const int lane = tid & 63;
    const int wave = tid >> 6;
    const int lr = lane & 15, q = lane >> 4;

    // XCD-paired stream mapping: bids 16p+x and 16p+x+8 (same XCD) take the
    // two col-halves of rc-stream st = p*8+x.
    const int bid = blockIdx.x;
    const int xcd = bid & 7;
    const int sg  = bid >> 3;          // 0..95
    const int h   = sg & 1;            // col half
    const int st  = (sg >> 1) * 8 + xcd;   // 0..383
    // 8192 = 384*21 + 128: streams 0..127 do 22 chunks, rest 21.
    const int nit = (st < 128) ? 22 : 21;

    // ---- this wave's 32-col W fragment set: 16 x bf16x8 = 64 regs ----
    const int nb  = h * 2 + (wave >> 1);
    const int tl0 = (wave & 1) * 2;
    const __bf16* wf = WF + (size_t)nb * (8 * 4 * 512) + lane * 8;
    bf16x8 bW[8][2];
#pragma unroll
    for (int c = 0; c < 8; ++c)
#pragma unroll
        for (int t = 0; t < 2; ++t)
            bW[c][t] = *(const bf16x8*)(wf + (c * 4 + tl0 + t) * 512);

    float bv[2];
#pragma unroll
    for (int t = 0; t < 2; ++t) bv[t] = bias[h * 128 + wave * 32 + t * 16 + lr];

    // ---- staging: wave stages rows wave*4..wave*4+3, 1 KB each.
    // LDS dest linear (base + lane*16); source byte offset pre-swizzled:
    // sw(r) = ((r&7)<<5) | ((r&8)<<1)  -> read-side 2-way conflicts only.
    int srcoff[4];
#pragma unroll
    for (int k = 0; k < 4; ++k) {
        const int r = wave * 4 + k;
        srcoff[k] = (lane * 16) ^ (((r & 7) << 5) | ((r & 8) << 1));
    }
    const int swr = ((lr & 7) << 3) | ((lr & 8) >> 1);   // word-granular read XOR

    // ---- prologue: stage chunks 0,1 into bufs 0,1; wait chunk 0 only ----
#pragma unroll
    for (int p = 0; p < 2; ++p) {
        const int rc = st + p * NSTREAM;
#pragma unroll
        for (int k = 0; k < 4; ++k)
            gload16((const char*)X + (size_t)(rc * 16 + wave * 4 + k) * 1024 + srcoff[k],
                    (char*)&sX[p][(wave * 4 + k) * 256]);
    }
    asm volatile("s_waitcnt vmcnt(4)" ::: "memory");
    __builtin_amdgcn_s_barrier();
    asm volatile("" ::: "memory");

    int cur = 0;
#pragma unroll 1
    for (int it = 0; it < nit; ++it) {
        // prefetch chunk it+2 into buffer (cur+2)%3 (DMA, no VGPRs)
        if (it + 2 < nit) {
            int b2 = cur + 2; if (b2 >= 3) b2 -= 3;
            const int rcn = st + (it + 2) * NSTREAM;
#pragma unroll
            for (int k = 0; k < 4; ++k)
                gload16((const char*)X + (size_t)(rcn * 16 + wave * 4 + k) * 1024 + srcoff[k],
                        (char*)&sX[b2][(wave * 4 + k) * 256]);
        }

        // ---- compute: 16 rows x 32 cols per wave, K=256 ----
        const int rc = st + it * NSTREAM;
        const float* sxr = &sX[cur][lr * 256];
        f32x4 acc0 = {0.f, 0.f, 0.f, 0.f};
        f32x4 acc1 = {0.f, 0.f, 0.f, 0.f};
#pragma unroll
        for (int c = 0; c < 8; ++c) {
            const int b0 = c * 32 + q * 8;
            f32x4 lo = *(const f32x4*)(sxr + (b0 ^ swr));
            f32x4 hi = *(const f32x4*)(sxr + ((b0 + 4) ^ swr));
            bf16x8 a;
            a[0] = (__bf16)lo[0]; a[1] = (__bf16)lo[1];
            a[2] = (__bf16)lo[2]; a[3] = (__bf16)lo[3];
            a[4] = (__bf16)hi[0]; a[5] = (__bf16)hi[1];
            a[6] = (__bf16)hi[2]; a[7] = (__bf16)hi[3];
            acc0 = __builtin_amdgcn_mfma_f32_16x16x32_bf16(a, bW[c][0], acc0, 0, 0, 0);
            acc1 = __builtin_amdgcn_mfma_f32_16x16x32_bf16(a, bW[c][1], acc1, 0, 0, 0);
        }

        // ---- epilogue: bias + tanh, direct NT scalar stores (4x64B segs/instr) ----
        float* yb = Y + (size_t)(rc * 16 + q * 4) * HIDDEN + h * 128 + wave * 32 + lr;
#pragma unroll
        for (int t = 0; t < 2; ++t)
#pragma unroll
            for (int i = 0; i < 4; ++i) {
                float z = (t ? acc1[i] : acc0[i]) + bv[t];
                z = fminf(fmaxf(z, -10.f), 10.f);
                const float e2 = __expf(2.0f * z);
                __builtin_nontemporal_store(__fdividef(e2 - 1.0f, e2 + 1.0f),
                                            yb + (size_t)i * HIDDEN + t * 16);
            }

        // In-order outstanding: [g(it+1):4][s(it-1):8][g(it+2):4][s(it):8].
        // vmcnt(12) drains g(it+1) (issued a FULL iteration ago) and
        // s(it-1) (one iteration of ack slack). Never waits on fresh ops.
        asm volatile("s_waitcnt vmcnt(12)" ::: "memory");
        __builtin_amdgcn_s_barrier();
        asm volatile("" ::: "memory");
        cur = (cur == 2) ? 0 : cur + 1;
    }
}

extern "C" void kernel_launch(void* const* d_in, const int* in_sizes, int n_in,
                              void* d_out, int out_size, void* d_ws, size_t ws_size,
                              hipStream_t stream) {
    const float* X    = (const float*)d_in[0];
    const float* W    = (const float*)d_in[1];
    const float* bias = (const float*)d_in[2];
    float* Y          = (float*)d_out;
    __bf16* WF        = (__bf16*)d_ws;     // 65536 bf16 = 128 KB

    wfrag_kernel<<<dim3(32), dim3(256), 0, stream>>>(W, WF);
    rotor_kernel<<<dim3(NBLK), dim3(256), 0, stream>>>(X, WF, bias, Y);
}

// Round 6
// 245.882 us; speedup vs baseline: 1.0262x; 1.0262x over previous
//
#include <hip/hip_runtime.h>
#include <hip/hip_bf16.h>

// tanh(X @ W^T + b): M=131072, N=K=256, fp32 in/out.
// R8 (resubmit after container failure): R7 with NT removed from stores
// (single-variable A/B). Theory: vmcnt retires IN ORDER, so the end-of-iter
// vmcnt(12) waits on S(k-1); nt-flagged scalar stores ack from the HBM path
// (slow, and caused 1.26x write amp from unmerged 64B partials). Plain
// stores ack from L2 (~200cyc, issued a full iteration earlier => free) and
// L2 merges segments into full lines. Everything else identical: 16-row
// chunk x 128 cols per block, 4 waves x 32 cols (bW[8][2]=64 regs), fp32 X
// via global_load_lds with pre-swizzled source (0 bank conflicts),
// distance-2 prefetch, triple-buffer 48 KB LDS, XCD-paired col-half
// siblings, 768 blocks, 3 blocks/CU.

#define HIDDEN 256
#define M_TOTAL (16 * 8192)
#define NBLK 768
#define NSTREAM 384          // NBLK/2 rc-streams, 2 col-half blocks each

using bf16x8 = __attribute__((ext_vector_type(8))) __bf16;
using f32x4  = __attribute__((ext_vector_type(4))) float;

__device__ __forceinline__ void gload16(const void* g, void* l) {
    __builtin_amdgcn_global_load_lds(
        (const __attribute__((address_space(1))) void*)g,
        (__attribute__((address_space(3))) void*)l, 16, 0, 0);
}

// WF[((nb*8 + c)*4 + t)*512 + lane*8 + j] =
//   bf16( W[(nb*64 + t*16 + (lane&15))*256 + c*32 + (lane>>4)*8 + j] )
__global__ __launch_bounds__(256) void wfrag_kernel(const float* __restrict__ W,
                                                    __bf16* __restrict__ WF) {
    const int gid  = blockIdx.x * 256 + threadIdx.x;   // 0..8191
    const int lane = gid & 63;
    const int t    = (gid >> 6) & 3;
    const int c    = (gid >> 8) & 7;
    const int nb   = gid >> 11;
    const int lr = lane & 15, q = lane >> 4;
    const float* src = W + (size_t)(nb * 64 + t * 16 + lr) * HIDDEN + c * 32 + q * 8;
    float4 lo = *(const float4*)src;
    float4 hi = *(const float4*)(src + 4);
    bf16x8 v;
    v[0] = (__bf16)lo.x; v[1] = (__bf16)lo.y; v[2] = (__bf16)lo.z; v[3] = (__bf16)lo.w;
    v[4] = (__bf16)hi.x; v[5] = (__bf16)hi.y; v[6] = (__bf16)hi.z; v[7] = (__bf16)hi.w;
    *(bf16x8*)(WF + (size_t)gid * 8) = v;
}

__global__ __launch_bounds__(256, 3) void rotor_kernel(const float* __restrict__ X,
                                                       const __bf16* __restrict__ WF,
                                                       const float* __restrict__ bias,
                                                       float* __restrict__ Y) {
    // X triple-buffer: 3 x 16 rows x 256 fp32 = 48 KB.
    __shared__ __align__(16) float sX[3][16 * 256];

    const int tid  = threadIdx.x;
    const int lane = tid & 63;
    const int wave = tid >> 6;
    const int lr = lane & 15, q = lane >> 4;

    // XCD-paired stream mapping: bids 16p+x and 16p+x+8 (same XCD) take the
    // two col-halves of rc-stream st = p*8+x.
    const int bid = blockIdx.x;
    const int xcd = bid & 7;
    const int sg  = bid >> 3;          // 0..95
    const int h   = sg & 1;            // col half
    const int st  = (sg >> 1) * 8 + xcd;   // 0..383
    // 8192 = 384*21 + 128: streams 0..127 do 22 chunks, rest 21.
    const int nit = (st < 128) ? 22 : 21;

    // ---- this wave's 32-col W fragment set: 16 x bf16x8 = 64 regs ----
    const int nb  = h * 2 + (wave >> 1);
    const int tl0 = (wave & 1) * 2;
    const __bf16* wf = WF + (size_t)nb * (8 * 4 * 512) + lane * 8;
    bf16x8 bW[8][2];
#pragma unroll
    for (int c = 0; c < 8; ++c)
#pragma unroll
        for (int t = 0; t < 2; ++t)
            bW[c][t] = *(const bf16x8*)(wf + (c * 4 + tl0 + t) * 512);

    float bv[2];
#pragma unroll
    for (int t = 0; t < 2; ++t) bv[t] = bias[h * 128 + wave * 32 + t * 16 + lr];

    // ---- staging: wave stages rows wave*4..wave*4+3, 1 KB each.
    // LDS dest linear (base + lane*16); source byte offset pre-swizzled:
    // sw(r) = ((r&7)<<5) | ((r&8)<<1)  -> read-side 2-way conflicts only.
    int srcoff[4];
#pragma unroll
    for (int k = 0; k < 4; ++k) {
        const int r = wave * 4 + k;
        srcoff[k] = (lane * 16) ^ (((r & 7) << 5) | ((r & 8) << 1));
    }
    const int swr = ((lr & 7) << 3) | ((lr & 8) >> 1);   // word-granular read XOR

    // ---- prologue: stage chunks 0,1 into bufs 0,1; wait chunk 0 only ----
#pragma unroll
    for (int p = 0; p < 2; ++p) {
        const int rc = st + p * NSTREAM;
#pragma unroll
        for (int k = 0; k < 4; ++k)
            gload16((const char*)X + (size_t)(rc * 16 + wave * 4 + k) * 1024 + srcoff[k],
                    (char*)&sX[p][(wave * 4 + k) * 256]);
    }
    asm volatile("s_waitcnt vmcnt(4)" ::: "memory");
    __builtin_amdgcn_s_barrier();
    asm volatile("" ::: "memory");

    int cur = 0;
#pragma unroll 1
    for (int it = 0; it < nit; ++it) {
        // prefetch chunk it+2 into buffer (cur+2)%3 (DMA, no VGPRs)
        if (it + 2 < nit) {
            int b2 = cur + 2; if (b2 >= 3) b2 -= 3;
            const int rcn = st + (it + 2) * NSTREAM;
#pragma unroll
            for (int k = 0; k < 4; ++k)
                gload16((const char*)X + (size_t)(rcn * 16 + wave * 4 + k) * 1024 + srcoff[k],
                        (char*)&sX[b2][(wave * 4 + k) * 256]);
        }

        // ---- compute: 16 rows x 32 cols per wave, K=256 ----
        const int rc = st + it * NSTREAM;
        const float* sxr = &sX[cur][lr * 256];
        f32x4 acc0 = {0.f, 0.f, 0.f, 0.f};
        f32x4 acc1 = {0.f, 0.f, 0.f, 0.f};
#pragma unroll
        for (int c = 0; c < 8; ++c) {
            const int b0 = c * 32 + q * 8;
            f32x4 lo = *(const f32x4*)(sxr + (b0 ^ swr));
            f32x4 hi = *(const f32x4*)(sxr + ((b0 + 4) ^ swr));
            bf16x8 a;
            a[0] = (__bf16)lo[0]; a[1] = (__bf16)lo[1];
            a[2] = (__bf16)lo[2]; a[3] = (__bf16)lo[3];
            a[4] = (__bf16)hi[0]; a[5] = (__bf16)hi[1];
            a[6] = (__bf16)hi[2]; a[7] = (__bf16)hi[3];
            acc0 = __builtin_amdgcn_mfma_f32_16x16x32_bf16(a, bW[c][0], acc0, 0, 0, 0);
            acc1 = __builtin_amdgcn_mfma_f32_16x16x32_bf16(a, bW[c][1], acc1, 0, 0, 0);
        }

        // ---- epilogue: bias + tanh, direct scalar stores (L2-acked, merged) ----
        float* yb = Y + (size_t)(rc * 16 + q * 4) * HIDDEN + h * 128 + wave * 32 + lr;
#pragma unroll
        for (int t = 0; t < 2; ++t)
#pragma unroll
            for (int i = 0; i < 4; ++i) {
                float z = (t ? acc1[i] : acc0[i]) + bv[t];
                z = fminf(fmaxf(z, -10.f), 10.f);
                const float e2 = __expf(2.0f * z);
                yb[(size_t)i * HIDDEN + t * 16] = __fdividef(e2 - 1.0f, e2 + 1.0f);
            }

        // In-order outstanding (oldest->newest): [G(it+1):4][S(it-1):8]
        // [G(it+2):4][S(it):8]. vmcnt(12) retires G(it+1) (issued 1.5 iters
        // ago) + S(it-1) (L2-acked, issued a full iteration ago — free).
        asm volatile("s_waitcnt vmcnt(12)" ::: "memory");
        __builtin_amdgcn_s_barrier();
        asm volatile("" ::: "memory");
        cur = (cur == 2) ? 0 : cur + 1;
    }
}

extern "C" void kernel_launch(void* const* d_in, const int* in_sizes, int n_in,
                              void* d_out, int out_size, void* d_ws, size_t ws_size,
                              hipStream_t stream) {
    const float* X    = (const float*)d_in[0];
    const float* W    = (const float*)d_in[1];
    const float* bias = (const float*)d_in[2];
    float* Y          = (float*)d_out;
    __bf16* WF        = (__bf16*)d_ws;     // 65536 bf16 = 128 KB

    wfrag_kernel<<<dim3(32), dim3(256), 0, stream>>>(W, WF);
    rotor_kernel<<<dim3(NBLK), dim3(256), 0, stream>>>(X, WF, bias, Y);
}

// Round 7
// 242.700 us; speedup vs baseline: 1.0397x; 1.0131x over previous
//
#include <hip/hip_runtime.h>
#include <hip/hip_bf16.h>

// tanh(X @ W^T + b): M=131072, N=K=256, fp32 in/out.
// R9: 32x32x16 MFMA + bf16 fragment-order LDS staging (reg-staged, cvt once).
// Block = 32-row chunk x 128 cols (col-half via XCD-paired sibling), 4 waves
// x 32 cols, bW[16] = 64 regs/wave. Per iter: cvt+ds_write chunk(it+1) from
// regs, issue loads chunk(it+2), compute chunk(it) via 16 linear
// ds_read_b128 (0 conflicts) + 16 MFMA, epilogue direct stores (128B segs),
// lgkmcnt-only drain + raw barrier (loads/stores stay in flight across it).
// LDS read traffic halved vs R8 (bf16, 2x A-reuse of 32x32), redundant
// 4x cvt eliminated, barriers per row halved. 768 blocks, 3/CU, 32 KB LDS.

#define HIDDEN 256
#define M_TOTAL (16 * 8192)
#define NBLK 768
#define NSTREAM 384          // rc-streams over 4096 32-row chunks
#define NCHUNK 4096

using bf16x8  = __attribute__((ext_vector_type(8))) __bf16;
using f32x4   = __attribute__((ext_vector_type(4))) float;
using f32x16  = __attribute__((ext_vector_type(16))) float;

__device__ __forceinline__ bf16x8 cvt8(float4 a, float4 b) {
    bf16x8 v;
    v[0] = (__bf16)a.x; v[1] = (__bf16)a.y; v[2] = (__bf16)a.z; v[3] = (__bf16)a.w;
    v[4] = (__bf16)b.x; v[5] = (__bf16)b.y; v[6] = (__bf16)b.z; v[7] = (__bf16)b.w;
    return v;
}

// B-fragments for mfma_f32_32x32x16_bf16, col-group g (32 cols), k-frag kf:
// WF[((g*16 + kf)*64 + lane)*8 + j] = bf16( W[g*32 + (lane&31)][kf*16 + (lane>>5)*8 + j] )
__global__ __launch_bounds__(256) void wfrag_kernel(const float* __restrict__ W,
                                                    __bf16* __restrict__ WF) {
    const int gid  = blockIdx.x * 256 + threadIdx.x;   // 0..8191
    const int lane = gid & 63;
    const int kf   = (gid >> 6) & 15;
    const int g    = gid >> 10;
    const float* src = W + (size_t)(g * 32 + (lane & 31)) * HIDDEN
                         + kf * 16 + (lane >> 5) * 8;
    float4 lo = *(const float4*)src;
    float4 hi = *(const float4*)(src + 4);
    *(bf16x8*)(WF + (size_t)gid * 8) = cvt8(lo, hi);
}

__global__ __launch_bounds__(256, 3) void rotor_kernel(const float* __restrict__ X,
                                                       const __bf16* __restrict__ WF,
                                                       const float* __restrict__ bias,
                                                       float* __restrict__ Y) {
    // A-fragment double buffer: 2 x (16 kf x 64 lanes x 8 bf16) = 32 KB.
    __shared__ __align__(16) __bf16 sA[2][8192];

    const int tid  = threadIdx.x;
    const int lane = tid & 63;
    const int wave = tid >> 6;
    const int col  = lane & 31;
    const int hi   = lane >> 5;

    // XCD-paired stream mapping: bids 16p+x / 16p+x+8 share rc-stream st.
    const int bid = blockIdx.x;
    const int xcd = bid & 7;
    const int sg  = bid >> 3;
    const int h   = sg & 1;                 // col half
    const int st  = (sg >> 1) * 8 + xcd;    // 0..383
    // 4096 = 384*10 + 256: streams 0..255 do 11 chunks, rest 10.
    const int nit = (st < 256) ? 11 : 10;

    // ---- this wave's 32-col B fragment set: 16 x bf16x8 = 64 regs ----
    const __bf16* wf = WF + (size_t)(h * 4 + wave) * 8192 + lane * 8;
    bf16x8 bW[16];
#pragma unroll
    for (int kf = 0; kf < 16; ++kf)
        bW[kf] = *(const bf16x8*)(wf + kf * 512);

    const float bv = bias[h * 128 + wave * 32 + col];

    // ---- staging map: thread (r = tid>>3, c0 = tid&7) owns row r,
    // k = c0*32..+31 (128B global, coalesced 8 threads/row). Fragment-order
    // write offsets (bf16 elems): wo, wo+256, wo+512, wo+768.
    const int r  = tid >> 3;
    const int c0 = tid & 7;
    const int wo = c0 * 1024 + r * 8;
    const float* xcol = X + (size_t)r * HIDDEN + c0 * 32;

    float4 xr[8];
    auto loadx = [&](int rc) {
        const float* xs = xcol + (size_t)rc * 32 * HIDDEN;
#pragma unroll
        for (int i = 0; i < 8; ++i) xr[i] = *(const float4*)(xs + i * 4);
    };
    auto stage = [&](__bf16* sbuf) {
        bf16x8 v0 = cvt8(xr[0], xr[1]);
        bf16x8 v1 = cvt8(xr[2], xr[3]);
        bf16x8 v2 = cvt8(xr[4], xr[5]);
        bf16x8 v3 = cvt8(xr[6], xr[7]);
        *(bf16x8*)(sbuf + wo)       = v0;
        *(bf16x8*)(sbuf + wo + 256) = v1;
        *(bf16x8*)(sbuf + wo + 512) = v2;
        *(bf16x8*)(sbuf + wo + 768) = v3;
    };

    // ---- prologue: stage chunk0 -> buf0; load chunk1 into regs ----
    loadx(st);
    stage(&sA[0][0]);
    loadx(st + NSTREAM);
    asm volatile("s_waitcnt lgkmcnt(0)" ::: "memory");
    __builtin_amdgcn_s_barrier();
    asm volatile("" ::: "memory");

#pragma unroll 1
    for (int it = 0; it < nit; ++it) {
        // cvt + write chunk(it+1) into the other buffer (compiler inserts
        // the precise vmcnt for xr here; stores are newer, stay in flight)
        if (it + 1 < nit) stage(&sA[(it + 1) & 1][0]);

        // issue loads for chunk(it+2): a full iteration of latency cover
        if (it + 2 < nit) loadx(st + (it + 2) * NSTREAM);

        // ---- compute: 32 rows x 32 cols, K=256, linear frag reads ----
        const __bf16* ab = &sA[it & 1][lane * 8];
        f32x16 acc = {0.f, 0.f, 0.f, 0.f, 0.f, 0.f, 0.f, 0.f,
                      0.f, 0.f, 0.f, 0.f, 0.f, 0.f, 0.f, 0.f};
#pragma unroll
        for (int kf = 0; kf < 16; ++kf) {
            bf16x8 a = *(const bf16x8*)(ab + kf * 512);
            acc = __builtin_amdgcn_mfma_f32_32x32x16_bf16(a, bW[kf], acc, 0, 0, 0);
        }

        // ---- epilogue: bias + tanh, direct stores (2x128B segs/instr) ----
        // C layout: col = lane&31, row = (reg&3) + 8*(reg>>2) + 4*(lane>>5)
        const int rc = st + it * NSTREAM;
        float* yb = Y + (size_t)rc * 32 * HIDDEN + h * 128 + wave * 32 + col;
#pragma unroll
        for (int g2 = 0; g2 < 4; ++g2)
#pragma unroll
            for (int rr = 0; rr < 4; ++rr) {
                const int row = rr + 8 * g2 + 4 * hi;
                float z = acc[g2 * 4 + rr] + bv;
                z = fminf(fmaxf(z, -10.f), 10.f);
                const float e2 = __expf(2.0f * z);
                yb[(size_t)row * HIDDEN] = __fdividef(e2 - 1.0f, e2 + 1.0f);
            }

        // drain LDS writes only; global loads/stores stay in flight
        asm volatile("s_waitcnt lgkmcnt(0)" ::: "memory");
        __builtin_amdgcn_s_barrier();
        asm volatile("" ::: "memory");
    }
}

extern "C" void kernel_launch(void* const* d_in, const int* in_sizes, int n_in,
                              void* d_out, int out_size, void* d_ws, size_t ws_size,
                              hipStream_t stream) {
    const float* X    = (const float*)d_in[0];
    const float* W    = (const float*)d_in[1];
    const float* bias = (const float*)d_in[2];
    float* Y          = (float*)d_out;
    __bf16* WF        = (__bf16*)d_ws;     // 65536 bf16 = 128 KB

    wfrag_kernel<<<dim3(32), dim3(256), 0, stream>>>(W, WF);
    rotor_kernel<<<dim3(NBLK), dim3(256), 0, stream>>>(X, WF, bias, Y);
}

// Round 8
// 242.571 us; speedup vs baseline: 1.0403x; 1.0005x over previous
//
#include <hip/hip_runtime.h>
#include <hip/hip_bf16.h>

// tanh(X @ W^T + b): M=131072, N=K=256, fp32 in/out.
// R10: R9 + (1) XOR bank-swizzle on fragment staging: write slot l16^c0,
// read lane^(kf>>1) — fixes the 8-way ds_write conflict (8-lane tid-groups
// share r, vary c0=kf>>1 which lived in non-bank addr bits); (2) 4 blocks/CU
// (launch_bounds(256,4), NBLK=1024, LDS 128KB/CU) -> 16 waves/CU. R9 model:
// wall was occupancy x per-wave-busy bound (3 waves/SIMD x ~2300 busy cyc
// vs 6470 wall = 33% ceiling = measured). 512 streams x exactly 8 chunks.

#define HIDDEN 256
#define M_TOTAL (16 * 8192)
#define NBLK 1024
#define NSTREAM 512          // rc-streams over 4096 32-row chunks, 8 each

using bf16x8  = __attribute__((ext_vector_type(8))) __bf16;
using f32x4   = __attribute__((ext_vector_type(4))) float;
using f32x16  = __attribute__((ext_vector_type(16))) float;

__device__ __forceinline__ bf16x8 cvt8(float4 a, float4 b) {
    bf16x8 v;
    v[0] = (__bf16)a.x; v[1] = (__bf16)a.y; v[2] = (__bf16)a.z; v[3] = (__bf16)a.w;
    v[4] = (__bf16)b.x; v[5] = (__bf16)b.y; v[6] = (__bf16)b.z; v[7] = (__bf16)b.w;
    return v;
}

// B-fragments for mfma_f32_32x32x16_bf16, col-group g (32 cols), k-frag kf:
// WF[((g*16 + kf)*64 + lane)*8 + j] = bf16( W[g*32 + (lane&31)][kf*16 + (lane>>5)*8 + j] )
__global__ __launch_bounds__(256) void wfrag_kernel(const float* __restrict__ W,
                                                    __bf16* __restrict__ WF) {
    const int gid  = blockIdx.x * 256 + threadIdx.x;   // 0..8191
    const int lane = gid & 63;
    const int kf   = (gid >> 6) & 15;
    const int g    = gid >> 10;
    const float* src = W + (size_t)(g * 32 + (lane & 31)) * HIDDEN
                         + kf * 16 + (lane >> 5) * 8;
    float4 lo = *(const float4*)src;
    float4 hi = *(const float4*)(src + 4);
    *(bf16x8*)(WF + (size_t)gid * 8) = cvt8(lo, hi);
}

__global__ __launch_bounds__(256, 4) void rotor_kernel(const float* __restrict__ X,
                                                       const __bf16* __restrict__ WF,
                                                       const float* __restrict__ bias,
                                                       float* __restrict__ Y) {
    // A-fragment double buffer: 2 x (16 kf x 64 slots x 8 bf16) = 32 KB.
    __shared__ __align__(16) __bf16 sA[2][8192];

    const int tid  = threadIdx.x;
    const int lane = tid & 63;
    const int wave = tid >> 6;
    const int col  = lane & 31;
    const int hi   = lane >> 5;

    // XCD-paired stream mapping: bids 16p+x / 16p+x+8 share rc-stream st.
    const int bid = blockIdx.x;
    const int xcd = bid & 7;
    const int sg  = bid >> 3;               // 0..127
    const int h   = sg & 1;                 // col half
    const int st  = (sg >> 1) * 8 + xcd;    // 0..511; 8 chunks each, exact

    // ---- this wave's 32-col B fragment set: 16 x bf16x8 = 64 regs ----
    const __bf16* wf = WF + (size_t)(h * 4 + wave) * 8192 + lane * 8;
    bf16x8 bW[16];
#pragma unroll
    for (int kf = 0; kf < 16; ++kf)
        bW[kf] = *(const bf16x8*)(wf + kf * 512);

    const float bv = bias[h * 128 + wave * 32 + col];

    // ---- staging map: thread (r = tid>>3, c0 = tid&7) owns row r,
    // k = c0*32..+31 (128B global, coalesced 8 threads/row). Fragment slots
    // XOR-swizzled: slot l16 -> l16 ^ c0 (c0 = kf>>1 for both kf this thread
    // writes) so each 8-lane tid-group (fixed r, c0=0..7) is a bank perm.
    const int r  = tid >> 3;
    const int c0 = tid & 7;
    const int wo = c0 * 1024 + (r ^ c0) * 8;
    const float* xcol = X + (size_t)r * HIDDEN + c0 * 32;

    float4 xr[8];
    auto loadx = [&](int rc) {
        const float* xs = xcol + (size_t)rc * 32 * HIDDEN;
#pragma unroll
        for (int i = 0; i < 8; ++i) xr[i] = *(const float4*)(xs + i * 4);
    };
    auto stage = [&](__bf16* sbuf) {
        bf16x8 v0 = cvt8(xr[0], xr[1]);
        bf16x8 v1 = cvt8(xr[2], xr[3]);
        bf16x8 v2 = cvt8(xr[4], xr[5]);
        bf16x8 v3 = cvt8(xr[6], xr[7]);
        *(bf16x8*)(sbuf + wo)       = v0;   // kf=2c0,   l16 = r
        *(bf16x8*)(sbuf + wo + 256) = v1;   // kf=2c0,   l16 = r+32
        *(bf16x8*)(sbuf + wo + 512) = v2;   // kf=2c0+1, l16 = r
        *(bf16x8*)(sbuf + wo + 768) = v3;   // kf=2c0+1, l16 = r+32
    };

    // ---- prologue: stage chunk0 -> buf0; load chunk1 into regs ----
    loadx(st);
    stage(&sA[0][0]);
    loadx(st + NSTREAM);
    asm volatile("s_waitcnt lgkmcnt(0)" ::: "memory");
    __builtin_amdgcn_s_barrier();
    asm volatile("" ::: "memory");

#pragma unroll 1
    for (int it = 0; it < 8; ++it) {
        // cvt + write chunk(it+1) into the other buffer (compiler inserts
        // the precise vmcnt for xr here; stores are newer, stay in flight)
        if (it < 7) stage(&sA[(it + 1) & 1][0]);

        // issue loads for chunk(it+2): a full iteration of latency cover
        if (it < 6) loadx(st + (it + 2) * NSTREAM);

        // ---- compute: 32 rows x 32 cols, K=256, swizzled frag reads ----
        const __bf16* sb = &sA[it & 1][0];
        f32x16 acc = {0.f, 0.f, 0.f, 0.f, 0.f, 0.f, 0.f, 0.f,
                      0.f, 0.f, 0.f, 0.f, 0.f, 0.f, 0.f, 0.f};
#pragma unroll
        for (int kf = 0; kf < 16; ++kf) {
            const int lx = lane ^ (kf >> 1);
            bf16x8 a = *(const bf16x8*)(sb + kf * 512 + lx * 8);
            acc = __builtin_amdgcn_mfma_f32_32x32x16_bf16(a, bW[kf], acc, 0, 0, 0);
        }

        // ---- epilogue: bias + tanh, direct stores (2x128B segs/instr) ----
        // C layout: col = lane&31, row = (reg&3) + 8*(reg>>2) + 4*(lane>>5)
        const int rc = st + it * NSTREAM;
        float* yb = Y + (size_t)rc * 32 * HIDDEN + h * 128 + wave * 32 + col;
#pragma unroll
        for (int g2 = 0; g2 < 4; ++g2)
#pragma unroll
            for (int rr = 0; rr < 4; ++rr) {
                const int row = rr + 8 * g2 + 4 * hi;
                float z = acc[g2 * 4 + rr] + bv;
                z = fminf(fmaxf(z, -10.f), 10.f);
                const float e2 = __expf(2.0f * z);
                yb[(size_t)row * HIDDEN] = __fdividef(e2 - 1.0f, e2 + 1.0f);
            }

        // drain LDS writes only; global loads/stores stay in flight
        asm volatile("s_waitcnt lgkmcnt(0)" ::: "memory");
        __builtin_amdgcn_s_barrier();
        asm volatile("" ::: "memory");
    }
}

extern "C" void kernel_launch(void* const* d_in, const int* in_sizes, int n_in,
                              void* d_out, int out_size, void* d_ws, size_t ws_size,
                              hipStream_t stream) {
    const float* X    = (const float*)d_in[0];
    const float* W    = (const float*)d_in[1];
    const float* bias = (const float*)d_in[2];
    float* Y          = (float*)d_out;
    __bf16* WF        = (__bf16*)d_ws;     // 65536 bf16 = 128 KB

    wfrag_kernel<<<dim3(32), dim3(256), 0, stream>>>(W, WF);
    rotor_kernel<<<dim3(NBLK), dim3(256), 0, stream>>>(X, WF, bias, Y);
}